// Round 10
// baseline (165.003 us; speedup 1.0000x reference)
//
#include <hip/hip_runtime.h>
#include <hip/hip_bf16.h>

#define B_ 128
#define S_ 200
#define QN_ 20000
#define V_ 128
#define K_ 128
#define C_ 64
#define SUM_ 128

using short8 = __attribute__((ext_vector_type(8))) short;
using f32x4  = __attribute__((ext_vector_type(4))) float;

// ---- fast activations (v_exp_f32-based; ~2 ulp, values here are O(1)) ----
__device__ __forceinline__ float fast_sigmoid(float x) { return 1.f / (1.f + __expf(-x)); }
__device__ __forceinline__ float fast_tanh(float x)    { return 1.f - 2.f / (__expf(2.f * x) + 1.f); }

// ---- dtype-generic loads (BF=true: bf16, BF=false: fp32) ----
template<bool BF>
__device__ __forceinline__ float ld(const void* p, long long i) {
    if (BF) return __bfloat162float(((const __hip_bfloat16*)p)[i]);
    return ((const float*)p)[i];
}
template<bool BF>
__device__ __forceinline__ float2 ld2(const void* p, long long i) {  // elems 2i, 2i+1
    if (BF) {
        __hip_bfloat162 v = ((const __hip_bfloat162*)p)[i];
        return make_float2(__bfloat162float(v.x), __bfloat162float(v.y));
    }
    return ((const float2*)p)[i];
}

__device__ __forceinline__ unsigned short f2bf(float v) {
    __hip_bfloat16 h = __float2bfloat16(v);
    unsigned short u;
    __builtin_memcpy(&u, &h, 2);
    return u;
}

// ---- dtype probe (r8 evidence: data is fp32; probe kept as insurance) ----
__device__ __forceinline__ int probe_flag_wave(const void* erase_b) {
    const unsigned* w = (const unsigned*)erase_b;
    const int lane = threadIdx.x & 63;
    const unsigned lo = w[lane] & 0xffffu;
    const float f = __uint_as_float(lo << 16);
    const unsigned long long bal = __ballot(!(fabsf(f) <= 0.5f));
    return (__popcll(bal) <= 8) ? 1 : 0;  // 1 = bf16
}

// ============ Prepack: weights -> bf16 MFMA B-fragments (80 KB) ============
__global__ __launch_bounds__(256) void dkvmn_prepack(
    const void* erase_W, const void* add_W, const void* key_memory,
    const void* erase_b, unsigned short* __restrict__ wpack)
{
    const int bf = probe_flag_wave(erase_b);
    const int fid = blockIdx.x * 256 + threadIdx.x;  // 0..5119
    if (fid >= 5120) return;
    const int lane = fid & 63;
    const int ks = (fid >> 6) & 3;
    const int wv = (fid >> 8) & 3;
    const int q  = fid >> 10;
    const int nt = wv + 4 * q;
    const void* Wsrc;
    int ncol, ldn;
    if (q < 2)      { Wsrc = erase_W;    ncol = nt * 16 + (lane & 15);        ldn = 128; }
    else if (q < 4) { Wsrc = add_W;      ncol = (nt - 8) * 16 + (lane & 15);  ldn = 128; }
    else            { Wsrc = key_memory; ncol = (nt - 16) * 16 + (lane & 15); ldn = 64; }
    const int k8 = (lane >> 4) * 8;
    unsigned short o[8];
    #pragma unroll
    for (int jj = 0; jj < 8; ++jj) {
        const long long idx = (long long)(ks * 32 + k8 + jj) * ldn + ncol;
        const float v = bf ? ld<true>(Wsrc, idx) : ld<false>(Wsrc, idx);
        o[jj] = f2bf(v);
    }
    *(uint4*)(wpack + (size_t)fid * 8) = *(const uint4*)o;
}

// ============ Phase 1 (MFMA): 32 positions/block, 800 blocks, 4 waves ==========
template<bool BF>
__device__ __forceinline__ void phase1_mfma_body(
    const void* q_emb, const void* i_emb,
    const void* erase_b, const void* add_b,
    const int* __restrict__ input, const unsigned short* __restrict__ wpack,
    float* __restrict__ e_buf, float* __restrict__ a_buf, float* __restrict__ w_buf,
    unsigned short* ivA, unsigned short* qvA, float* wlog, int* sidx, int* sqid)
{
    const int p0 = blockIdx.x * 32;
    const int t = threadIdx.x;      // 0..255
    const int wv = t >> 6;          // wave 0..3
    const int lane = t & 63;
    const int lrow = lane & 15;
    const int lk8 = (lane >> 4) * 8;

    if (t < 32) {
        const int ix = input[p0 + t];
        sidx[t] = ix;
        sqid[t] = ix > QN_ ? ix - QN_ : ix;
    }
    __syncthreads();

    // stage A: 2 tensors x 32 rows x 16 segs of 8 elems (fp32->bf16 convert)
    #pragma unroll
    for (int r = 0; r < 4; ++r) {
        const int j = t + 256 * r;          // 0..1023
        const int tensor = j >> 9;
        const int row = (j >> 4) & 31;
        const int seg = j & 15;
        const int gr = tensor ? sqid[row] : sidx[row];
        unsigned short* dst = (tensor ? qvA : ivA) + row * 136 + seg * 8;
        if (BF) {
            const unsigned short* src = (const unsigned short*)(tensor ? q_emb : i_emb);
            *(uint4*)dst = *(const uint4*)(src + (long long)gr * 128 + seg * 8);
        } else {
            const float* src = (const float*)(tensor ? q_emb : i_emb) + (long long)gr * 128 + seg * 8;
            const float4 f0 = *(const float4*)src;
            const float4 f1 = *(const float4*)(src + 4);
            unsigned short o[8] = {f2bf(f0.x), f2bf(f0.y), f2bf(f0.z), f2bf(f0.w),
                                   f2bf(f1.x), f2bf(f1.y), f2bf(f1.z), f2bf(f1.w)};
            *(uint4*)dst = *(const uint4*)o;
        }
    }

    // B fragments: single 16-B loads from prepacked buffer (L2-resident)
    short8 bfr[5][4];
    int nco[5];
    float biasq[4];
    #pragma unroll
    for (int q = 0; q < 5; ++q) {
        const int nt = wv + 4 * q;
        if (q < 2)      nco[q] = nt * 16 + lrow;
        else if (q < 4) nco[q] = (nt - 8) * 16 + lrow;
        else            nco[q] = (nt - 16) * 16 + lrow;
        if (q < 2)      biasq[q] = ld<BF>(erase_b, nco[q]);
        else if (q < 4) biasq[q] = ld<BF>(add_b, nco[q]);
        #pragma unroll
        for (int ks = 0; ks < 4; ++ks)
            bfr[q][ks] = *(const short8*)(wpack +
                ((size_t)(((q * 4 + wv) * 4 + ks) * 64 + lane)) * 8);
    }
    __syncthreads();

    // IV tiles: erase (q=0,1), add (q=2,3)
    #pragma unroll
    for (int mt = 0; mt < 2; ++mt) {
        short8 afr[4];
        const unsigned short* ar = ivA + (mt * 16 + lrow) * 136 + lk8;
        #pragma unroll
        for (int ks = 0; ks < 4; ++ks)
            afr[ks] = *(const short8*)(ar + ks * 32);
        #pragma unroll
        for (int q = 0; q < 4; ++q) {
            f32x4 acc = {0.f, 0.f, 0.f, 0.f};
            #pragma unroll
            for (int ks = 0; ks < 4; ++ks)
                acc = __builtin_amdgcn_mfma_f32_16x16x32_bf16(afr[ks], bfr[q][ks], acc, 0, 0, 0);
            float* dst = (q < 2) ? e_buf : a_buf;
            const int ncol = nco[q];
            const float bb = biasq[q];
            #pragma unroll
            for (int r = 0; r < 4; ++r) {
                const int prow = p0 + mt * 16 + (lane >> 4) * 4 + r;
                const float y = acc[r] + bb;
                dst[(size_t)prow * V_ + ncol] =
                    (q < 2) ? fast_sigmoid(y) : fast_tanh(y);
            }
        }
    }
    // QV key tile (q=4): logits -> LDS
    #pragma unroll
    for (int mt = 0; mt < 2; ++mt) {
        short8 afr[4];
        const unsigned short* ar = qvA + (mt * 16 + lrow) * 136 + lk8;
        #pragma unroll
        for (int ks = 0; ks < 4; ++ks)
            afr[ks] = *(const short8*)(ar + ks * 32);
        f32x4 acc = {0.f, 0.f, 0.f, 0.f};
        #pragma unroll
        for (int ks = 0; ks < 4; ++ks)
            acc = __builtin_amdgcn_mfma_f32_16x16x32_bf16(afr[ks], bfr[4][ks], acc, 0, 0, 0);
        #pragma unroll
        for (int r = 0; r < 4; ++r)
            wlog[(mt * 16 + (lane >> 4) * 4 + r) * 68 + nco[4]] = acc[r];
    }
    __syncthreads();

    // softmax over 64 logits/row: thread t -> row t>>3 (0..31), 8-col seg t&7
    {
        const int row = t >> 3;
        const int cs = t & 7;
        const float* wr = &wlog[row * 68 + cs * 8];
        float v[8];
        *(float4*)&v[0] = *(const float4*)&wr[0];
        *(float4*)&v[4] = *(const float4*)&wr[4];
        float m = v[0];
        #pragma unroll
        for (int ii = 1; ii < 8; ++ii) m = fmaxf(m, v[ii]);
        m = fmaxf(m, __shfl_xor(m, 1, 64));
        m = fmaxf(m, __shfl_xor(m, 2, 64));
        m = fmaxf(m, __shfl_xor(m, 4, 64));
        float s = 0.f;
        #pragma unroll
        for (int ii = 0; ii < 8; ++ii) { v[ii] = __expf(v[ii] - m); s += v[ii]; }
        s += __shfl_xor(s, 1, 64);
        s += __shfl_xor(s, 2, 64);
        s += __shfl_xor(s, 4, 64);
        const float inv = 1.f / s;
        float* wout = w_buf + (size_t)(p0 + row) * C_ + cs * 8;
        *(float4*)&wout[0] = make_float4(v[0]*inv, v[1]*inv, v[2]*inv, v[3]*inv);
        *(float4*)&wout[4] = make_float4(v[4]*inv, v[5]*inv, v[6]*inv, v[7]*inv);
    }
}

__global__ __launch_bounds__(256) void dkvmn_phase1_mfma(
    const void* q_emb, const void* i_emb,
    const void* erase_b, const void* add_b,
    const int* __restrict__ input, const unsigned short* __restrict__ wpack,
    float* e_buf, float* a_buf, float* w_buf)
{
    __shared__ unsigned short ivA[32 * 136];
    __shared__ unsigned short qvA[32 * 136];
    __shared__ float wlog[32 * 68];
    __shared__ int sidx[32], sqid[32];
    if (probe_flag_wave(erase_b))
        phase1_mfma_body<true>(q_emb, i_emb, erase_b, add_b, input, wpack,
                               e_buf, a_buf, w_buf, ivA, qvA, wlog, sidx, sqid);
    else
        phase1_mfma_body<false>(q_emb, i_emb, erase_b, add_b, input, wpack,
                                e_buf, a_buf, w_buf, ivA, qvA, wlog, sidx, sqid);
}

// ====== Phase 2: c-split x2, v-split x2; 512 blocks x 256 thr; tile 2v x 4c ======
__device__ __forceinline__ void scan_step24(float mem[2][4], float2 e2, float2 a2,
                                            float4 w4) {
    const float ev[2] = {e2.x, e2.y};
    const float av[2] = {a2.x, a2.y};
    const float wvv[4] = {w4.x, w4.y, w4.z, w4.w};
    #pragma unroll
    for (int i = 0; i < 2; ++i)
        #pragma unroll
        for (int j = 0; j < 4; ++j)
            mem[i][j] = fmaf(wvv[j], fmaf(-mem[i][j], ev[i], av[i]), mem[i][j]);
}

template<bool BF>
__device__ __forceinline__ void phase2_body(
    const void* q_emb, const void* key_memory, const void* init_value_memory,
    const int* __restrict__ target_id,
    const float* __restrict__ e_buf, const float* __restrict__ a_buf,
    const float* __restrict__ w_buf, float* __restrict__ part_buf,
    float* wtl)
{
    // b = bid&127: blocks {b, b+128, b+256, b+384} all land on XCD b%8.
    const int bid = blockIdx.x;
    const int b = bid & 127;
    const int sub = bid >> 7;       // 0..3
    const int ch = sub & 1;
    const int vh = sub >> 1;
    const int t = threadIdx.x;      // 0..255
    const int vg = t >> 3;          // 0..31
    const int cg = t & 7;           // 0..7
    const int v0 = vh * 64 + vg * 2;
    const int c0 = ch * 32 + cg * 4;

    float mem[2][4];
    #pragma unroll
    for (int i = 0; i < 2; ++i) {
        const float2 m01 = ld2<BF>(init_value_memory, ((v0 + i) * C_ + c0) >> 1);
        const float2 m23 = ld2<BF>(init_value_memory, ((v0 + i) * C_ + c0 + 2) >> 1);
        mem[i][0] = m01.x; mem[i][1] = m01.y; mem[i][2] = m23.x; mem[i][3] = m23.y;
    }

    const float* eb = e_buf + (size_t)b * S_ * V_ + v0;
    const float* ab = a_buf + (size_t)b * S_ * V_ + v0;
    const float* wb = w_buf + (size_t)b * S_ * C_ + c0;

    float2 pe[5], pa[5];
    float4 pw[5];
    #pragma unroll
    for (int k = 0; k < 5; ++k) {
        pe[k] = *(const float2*)(eb + (size_t)k * V_);
        pa[k] = *(const float2*)(ab + (size_t)k * V_);
        pw[k] = *(const float4*)(wb + (size_t)k * C_);
    }
    for (int s0 = 0; s0 < 195; s0 += 5) {
        #pragma unroll
        for (int k = 0; k < 5; ++k) {
            const float2 E = pe[k], A = pa[k];
            const float4 W = pw[k];
            const size_t sn = (size_t)(s0 + k + 5);     // <= 199
            pe[k] = *(const float2*)(eb + sn * V_);
            pa[k] = *(const float2*)(ab + sn * V_);
            pw[k] = *(const float4*)(wb + sn * C_);
            scan_step24(mem, E, A, W);
        }
    }
    #pragma unroll
    for (int k = 0; k < 5; ++k)
        scan_step24(mem, pe[k], pa[k], pw[k]);

    if (t < 64) {
        const long long qrow = (long long)target_id[b] * K_;
        float logit = 0.f;
        #pragma unroll 8
        for (int i = 0; i < K_; ++i)
            logit += ld<BF>(q_emb, qrow + i) * ld<BF>(key_memory, i * C_ + t);
        float m = logit;
        for (int off = 32; off > 0; off >>= 1)
            m = fmaxf(m, __shfl_xor(m, off, 64));
        const float ex = __expf(logit - m);
        float ssum = ex;
        for (int off = 32; off > 0; off >>= 1)
            ssum += __shfl_xor(ssum, off, 64);
        wtl[t] = ex / ssum;
    }
    __syncthreads();

    float wt4[4];
    *(float4*)wt4 = *(const float4*)&wtl[c0];
    float red[2];
    #pragma unroll
    for (int i = 0; i < 2; ++i)
        red[i] = mem[i][0]*wt4[0] + mem[i][1]*wt4[1] + mem[i][2]*wt4[2] + mem[i][3]*wt4[3];
    #pragma unroll
    for (int off = 1; off < 8; off <<= 1) {
        #pragma unroll
        for (int i = 0; i < 2; ++i)
            red[i] += __shfl_xor(red[i], off, 64);
    }
    if (cg == 0)
        *(float2*)(part_buf + ((size_t)ch * B_ + b) * V_ + v0) =
            make_float2(red[0], red[1]);
}

__global__ __launch_bounds__(256) void dkvmn_phase2(
    const void* q_emb, const void* key_memory, const void* init_value_memory,
    const void* erase_b,
    const int* __restrict__ target_id,
    const float* e_buf, const float* a_buf, const float* w_buf,
    float* part_buf)
{
    __shared__ float wtl[C_];
    if (probe_flag_wave(erase_b))
        phase2_body<true>(q_emb, key_memory, init_value_memory, target_id,
                          e_buf, a_buf, w_buf, part_buf, wtl);
    else
        phase2_body<false>(q_emb, key_memory, init_value_memory, target_id,
                           e_buf, a_buf, w_buf, part_buf, wtl);
}

// ================= Phase 3: summ mat-vec + scalar out =================
template<bool BF>
__device__ __forceinline__ void phase3_body(
    const void* q_emb, const void* summ_W, const void* summ_b,
    const void* out_W, const void* out_b,
    const int* __restrict__ target_id, const float* __restrict__ part_buf,
    void* outp, float* summl)
{
    const int b = blockIdx.x;
    const int t = threadIdx.x;  // 0..127
    const long long qrow = (long long)target_id[b] * K_;
    const float* pb0 = part_buf + (size_t)b * V_;
    const float* pb1 = part_buf + (size_t)(B_ + b) * V_;

    float acc = ld<BF>(summ_b, t);
    #pragma unroll 8
    for (int i = 0; i < 128; ++i)
        acc += (pb0[i] + pb1[i]) * ld<BF>(summ_W, i * SUM_ + t);
    #pragma unroll 8
    for (int i = 0; i < 128; ++i)
        acc += ld<BF>(q_emb, qrow + i) * ld<BF>(summ_W, (128 + i) * SUM_ + t);
    summl[t] = fast_tanh(acc);
    __syncthreads();

    if (t < 64) {
        float pacc = summl[t] * ld<BF>(out_W, t) + summl[t + 64] * ld<BF>(out_W, t + 64);
        for (int off = 32; off > 0; off >>= 1)
            pacc += __shfl_xor(pacc, off, 64);
        if (t == 0) {
            const float res = pacc + ld<BF>(out_b, 0);
            if (BF) ((__hip_bfloat16*)outp)[b] = __float2bfloat16(res);
            else    ((float*)outp)[b] = res;
        }
    }
}

__global__ __launch_bounds__(128) void dkvmn_phase3(
    const void* q_emb, const void* summ_W, const void* summ_b,
    const void* out_W, const void* out_b, const void* erase_b,
    const int* __restrict__ target_id, const float* part_buf,
    void* outp)
{
    __shared__ float summl[SUM_];
    if (probe_flag_wave(erase_b))
        phase3_body<true>(q_emb, summ_W, summ_b, out_W, out_b, target_id,
                          part_buf, outp, summl);
    else
        phase3_body<false>(q_emb, summ_W, summ_b, out_W, out_b, target_id,
                           part_buf, outp, summl);
}

extern "C" void kernel_launch(void* const* d_in, const int* in_sizes, int n_in,
                              void* d_out, int out_size, void* d_ws, size_t ws_size,
                              hipStream_t stream) {
    const void* q_emb             = d_in[0];
    const void* i_emb             = d_in[1];
    const void* key_memory        = d_in[2];
    const void* init_value_memory = d_in[3];
    const void* erase_W           = d_in[4];
    const void* erase_b           = d_in[5];
    const void* add_W             = d_in[6];
    const void* add_b             = d_in[7];
    const void* summ_W            = d_in[8];
    const void* summ_b            = d_in[9];
    const void* out_W             = d_in[10];
    const void* out_b             = d_in[11];
    const int* input     = (const int*)d_in[12];
    const int* target_id = (const int*)d_in[13];

    // ws: [e B*S*V f32][a B*S*V f32][w B*S*C f32][part 2*B*V f32][wpack 80KB]
    float* e_buf    = (float*)d_ws;
    float* a_buf    = e_buf + (size_t)B_ * S_ * V_;
    float* w_buf    = a_buf + (size_t)B_ * S_ * V_;
    float* part_buf = w_buf + (size_t)B_ * S_ * C_;
    unsigned short* wpack = (unsigned short*)(part_buf + (size_t)2 * B_ * V_);

    dkvmn_prepack<<<20, 256, 0, stream>>>(erase_W, add_W, key_memory, erase_b, wpack);
    dkvmn_phase1_mfma<<<(B_ * S_) / 32, 256, 0, stream>>>(
        q_emb, i_emb, erase_b, add_b, input, wpack, e_buf, a_buf, w_buf);
    dkvmn_phase2<<<4 * B_, 256, 0, stream>>>(
        q_emb, key_memory, init_value_memory, erase_b, target_id,
        e_buf, a_buf, w_buf, part_buf);
    dkvmn_phase3<<<B_, 128, 0, stream>>>(
        q_emb, summ_W, summ_b, out_W, out_b, erase_b, target_id, part_buf, d_out);
}

// Round 11
// 154.576 us; speedup vs baseline: 1.0675x; 1.0675x over previous
//
#include <hip/hip_runtime.h>
#include <hip/hip_bf16.h>
#include <hip/hip_fp16.h>

#define B_ 128
#define S_ 200
#define QN_ 20000
#define V_ 128
#define K_ 128
#define C_ 64
#define SUM_ 128
#define NCH 8           // scan chunks (S = 8 * 25)
#define CL 25           // steps per chunk

using short8 = __attribute__((ext_vector_type(8))) short;
using f32x4  = __attribute__((ext_vector_type(4))) float;

__device__ __forceinline__ float fast_sigmoid(float x) { return 1.f / (1.f + __expf(-x)); }
__device__ __forceinline__ float fast_tanh(float x)    { return 1.f - 2.f / (__expf(2.f * x) + 1.f); }

template<bool BF>
__device__ __forceinline__ float ld(const void* p, long long i) {
    if (BF) return __bfloat162float(((const __hip_bfloat16*)p)[i]);
    return ((const float*)p)[i];
}
template<bool BF>
__device__ __forceinline__ float2 ld2(const void* p, long long i) {
    if (BF) {
        __hip_bfloat162 v = ((const __hip_bfloat162*)p)[i];
        return make_float2(__bfloat162float(v.x), __bfloat162float(v.y));
    }
    return ((const float2*)p)[i];
}

__device__ __forceinline__ unsigned short f2bf(float v) {
    __hip_bfloat16 h = __float2bfloat16(v);
    unsigned short u;
    __builtin_memcpy(&u, &h, 2);
    return u;
}

__device__ __forceinline__ int probe_flag_wave(const void* erase_b) {
    const unsigned* w = (const unsigned*)erase_b;
    const int lane = threadIdx.x & 63;
    const unsigned lo = w[lane] & 0xffffu;
    const float f = __uint_as_float(lo << 16);
    const unsigned long long bal = __ballot(!(fabsf(f) <= 0.5f));
    return (__popcll(bal) <= 8) ? 1 : 0;  // 1 = bf16
}

// ============ Prepack: weights -> bf16 MFMA B-fragments (80 KB) ============
__global__ __launch_bounds__(256) void dkvmn_prepack(
    const void* erase_W, const void* add_W, const void* key_memory,
    const void* erase_b, unsigned short* __restrict__ wpack)
{
    const int bf = probe_flag_wave(erase_b);
    const int fid = blockIdx.x * 256 + threadIdx.x;  // 0..5119
    if (fid >= 5120) return;
    const int lane = fid & 63;
    const int ks = (fid >> 6) & 3;
    const int wv = (fid >> 8) & 3;
    const int q  = fid >> 10;
    const int nt = wv + 4 * q;
    const void* Wsrc;
    int ncol, ldn;
    if (q < 2)      { Wsrc = erase_W;    ncol = nt * 16 + (lane & 15);        ldn = 128; }
    else if (q < 4) { Wsrc = add_W;      ncol = (nt - 8) * 16 + (lane & 15);  ldn = 128; }
    else            { Wsrc = key_memory; ncol = (nt - 16) * 16 + (lane & 15); ldn = 64; }
    const int k8 = (lane >> 4) * 8;
    unsigned short o[8];
    #pragma unroll
    for (int jj = 0; jj < 8; ++jj) {
        const long long idx = (long long)(ks * 32 + k8 + jj) * ldn + ncol;
        const float v = bf ? ld<true>(Wsrc, idx) : ld<false>(Wsrc, idx);
        o[jj] = f2bf(v);
    }
    *(uint4*)(wpack + (size_t)fid * 8) = *(const uint4*)o;
}

// ============ Phase 1 (MFMA): 64 positions/block, 400 blocks (r9 shape) ==========
template<bool BF>
__device__ __forceinline__ void phase1_mfma_body(
    const void* q_emb, const void* i_emb,
    const void* erase_b, const void* add_b,
    const int* __restrict__ input, const unsigned short* __restrict__ wpack,
    float* __restrict__ e_buf, float* __restrict__ a_buf, float* __restrict__ w_buf,
    unsigned short* ivA, unsigned short* qvA, float* wlog, int* sidx, int* sqid)
{
    const int p0 = blockIdx.x * 64;
    const int t = threadIdx.x;      // 0..255
    const int wv = t >> 6;
    const int lane = t & 63;
    const int lrow = lane & 15;
    const int lk8 = (lane >> 4) * 8;

    if (t < 64) {
        const int ix = input[p0 + t];
        sidx[t] = ix;
        sqid[t] = ix > QN_ ? ix - QN_ : ix;
    }
    __syncthreads();

    #pragma unroll
    for (int r = 0; r < 8; ++r) {
        const int j = t + 256 * r;          // 0..2047
        const int tensor = j >> 10;
        const int row = (j >> 4) & 63;
        const int seg = j & 15;
        const int gr = tensor ? sqid[row] : sidx[row];
        unsigned short* dst = (tensor ? qvA : ivA) + row * 136 + seg * 8;
        if (BF) {
            const unsigned short* src = (const unsigned short*)(tensor ? q_emb : i_emb);
            *(uint4*)dst = *(const uint4*)(src + (long long)gr * 128 + seg * 8);
        } else {
            const float* src = (const float*)(tensor ? q_emb : i_emb) + (long long)gr * 128 + seg * 8;
            const float4 f0 = *(const float4*)src;
            const float4 f1 = *(const float4*)(src + 4);
            unsigned short o[8] = {f2bf(f0.x), f2bf(f0.y), f2bf(f0.z), f2bf(f0.w),
                                   f2bf(f1.x), f2bf(f1.y), f2bf(f1.z), f2bf(f1.w)};
            *(uint4*)dst = *(const uint4*)o;
        }
    }

    short8 bfr[5][4];
    int nco[5];
    float biasq[4];
    #pragma unroll
    for (int q = 0; q < 5; ++q) {
        const int nt = wv + 4 * q;
        if (q < 2)      nco[q] = nt * 16 + lrow;
        else if (q < 4) nco[q] = (nt - 8) * 16 + lrow;
        else            nco[q] = (nt - 16) * 16 + lrow;
        if (q < 2)      biasq[q] = ld<BF>(erase_b, nco[q]);
        else if (q < 4) biasq[q] = ld<BF>(add_b, nco[q]);
        #pragma unroll
        for (int ks = 0; ks < 4; ++ks)
            bfr[q][ks] = *(const short8*)(wpack +
                ((size_t)(((q * 4 + wv) * 4 + ks) * 64 + lane)) * 8);
    }
    __syncthreads();

    for (int mt = 0; mt < 4; ++mt) {
        short8 afr[4];
        const unsigned short* ar = ivA + (mt * 16 + lrow) * 136 + lk8;
        #pragma unroll
        for (int ks = 0; ks < 4; ++ks)
            afr[ks] = *(const short8*)(ar + ks * 32);
        #pragma unroll
        for (int q = 0; q < 4; ++q) {
            f32x4 acc = {0.f, 0.f, 0.f, 0.f};
            #pragma unroll
            for (int ks = 0; ks < 4; ++ks)
                acc = __builtin_amdgcn_mfma_f32_16x16x32_bf16(afr[ks], bfr[q][ks], acc, 0, 0, 0);
            float* dst = (q < 2) ? e_buf : a_buf;
            const int ncol = nco[q];
            const float bb = biasq[q];
            #pragma unroll
            for (int r = 0; r < 4; ++r) {
                const int prow = p0 + mt * 16 + (lane >> 4) * 4 + r;
                const float y = acc[r] + bb;
                dst[(size_t)prow * V_ + ncol] =
                    (q < 2) ? fast_sigmoid(y) : fast_tanh(y);
            }
        }
    }
    for (int mt = 0; mt < 4; ++mt) {
        short8 afr[4];
        const unsigned short* ar = qvA + (mt * 16 + lrow) * 136 + lk8;
        #pragma unroll
        for (int ks = 0; ks < 4; ++ks)
            afr[ks] = *(const short8*)(ar + ks * 32);
        f32x4 acc = {0.f, 0.f, 0.f, 0.f};
        #pragma unroll
        for (int ks = 0; ks < 4; ++ks)
            acc = __builtin_amdgcn_mfma_f32_16x16x32_bf16(afr[ks], bfr[4][ks], acc, 0, 0, 0);
        #pragma unroll
        for (int r = 0; r < 4; ++r)
            wlog[(mt * 16 + (lane >> 4) * 4 + r) * 68 + nco[4]] = acc[r];
    }
    __syncthreads();

    {
        const int row = t >> 2;
        const int cs = t & 3;
        const float* wr = &wlog[row * 68 + cs * 16];
        float v[16];
        #pragma unroll
        for (int ii = 0; ii < 4; ++ii)
            *(float4*)&v[ii * 4] = *(const float4*)&wr[ii * 4];
        float m = v[0];
        #pragma unroll
        for (int ii = 1; ii < 16; ++ii) m = fmaxf(m, v[ii]);
        m = fmaxf(m, __shfl_xor(m, 1, 64));
        m = fmaxf(m, __shfl_xor(m, 2, 64));
        float s = 0.f;
        #pragma unroll
        for (int ii = 0; ii < 16; ++ii) { v[ii] = __expf(v[ii] - m); s += v[ii]; }
        s += __shfl_xor(s, 1, 64);
        s += __shfl_xor(s, 2, 64);
        const float inv = 1.f / s;
        float* wout = w_buf + (size_t)(p0 + row) * C_ + cs * 16;
        #pragma unroll
        for (int ii = 0; ii < 4; ++ii)
            *(float4*)&wout[ii * 4] = make_float4(v[ii*4] * inv, v[ii*4+1] * inv,
                                                  v[ii*4+2] * inv, v[ii*4+3] * inv);
    }
}

__global__ __launch_bounds__(256) void dkvmn_phase1_mfma(
    const void* q_emb, const void* i_emb,
    const void* erase_b, const void* add_b,
    const int* __restrict__ input, const unsigned short* __restrict__ wpack,
    float* e_buf, float* a_buf, float* w_buf)
{
    __shared__ unsigned short ivA[64 * 136];
    __shared__ unsigned short qvA[64 * 136];
    __shared__ float wlog[64 * 68];
    __shared__ int sidx[64], sqid[64];
    if (probe_flag_wave(erase_b))
        phase1_mfma_body<true>(q_emb, i_emb, erase_b, add_b, input, wpack,
                               e_buf, a_buf, w_buf, ivA, qvA, wlog, sidx, sqid);
    else
        phase1_mfma_body<false>(q_emb, i_emb, erase_b, add_b, input, wpack,
                                e_buf, a_buf, w_buf, ivA, qvA, wlog, sidx, sqid);
}

// ====== Scan: affine-compose 25 steps/chunk; 1024 blocks; tile 4v x 8c ======
// Per element: (D, U) with D = prod(1 - e*w), U folded via y = d*y + a*w from y=0.
__global__ __launch_bounds__(256) void dkvmn_scan(
    const float* __restrict__ e_buf, const float* __restrict__ a_buf,
    const float* __restrict__ w_buf, __half2* __restrict__ du)
{
    const int bid = blockIdx.x;
    const int b = bid & 127;
    const int chunk = bid >> 7;     // 0..7
    const int t = threadIdx.x;      // 0..255
    const int vg = t >> 3;          // 0..31
    const int cg = t & 7;           // 0..7
    const int v0 = vg * 4, c0 = cg * 8;

    float ym[4][8], Dm[4][8];
    #pragma unroll
    for (int i = 0; i < 4; ++i)
        #pragma unroll
        for (int j = 0; j < 8; ++j) { ym[i][j] = 0.f; Dm[i][j] = 1.f; }

    const float* eb = e_buf + ((size_t)b * S_ + chunk * CL) * V_ + v0;
    const float* ab = a_buf + ((size_t)b * S_ + chunk * CL) * V_ + v0;
    const float* wb = w_buf + ((size_t)b * S_ + chunk * CL) * C_ + c0;

    #define SSTEP(E, A, W0, W1)                                                \
        do {                                                                   \
            const float ev[4] = {(E).x, (E).y, (E).z, (E).w};                  \
            const float av[4] = {(A).x, (A).y, (A).z, (A).w};                  \
            const float wvv[8] = {(W0).x, (W0).y, (W0).z, (W0).w,              \
                                  (W1).x, (W1).y, (W1).z, (W1).w};             \
            _Pragma("unroll")                                                  \
            for (int i = 0; i < 4; ++i) {                                      \
                _Pragma("unroll")                                              \
                for (int j = 0; j < 8; ++j) {                                  \
                    const float d = fmaf(-ev[i], wvv[j], 1.f);                 \
                    Dm[i][j] *= d;                                             \
                    ym[i][j] = fmaf(d, ym[i][j], av[i] * wvv[j]);              \
                }                                                              \
            }                                                                  \
        } while (0)

    // depth-2 pipeline over 25 steps: windows of 2 (steps 0..21), tail 22..24
    float4 pe[2], pa[2], pw0[2], pw1[2];
    #pragma unroll
    for (int k = 0; k < 2; ++k) {
        pe[k]  = *(const float4*)(eb + (size_t)k * V_);
        pa[k]  = *(const float4*)(ab + (size_t)k * V_);
        pw0[k] = *(const float4*)(wb + (size_t)k * C_);
        pw1[k] = *(const float4*)(wb + (size_t)k * C_ + 4);
    }
    for (int s0 = 0; s0 < 22; s0 += 2) {    // s0 = 0..20
        #pragma unroll
        for (int k = 0; k < 2; ++k) {
            const float4 E = pe[k], A = pa[k], W0 = pw0[k], W1 = pw1[k];
            const size_t sn = (size_t)(s0 + k + 2);   // <= 23
            pe[k]  = *(const float4*)(eb + sn * V_);
            pa[k]  = *(const float4*)(ab + sn * V_);
            pw0[k] = *(const float4*)(wb + sn * C_);
            pw1[k] = *(const float4*)(wb + sn * C_ + 4);
            SSTEP(E, A, W0, W1);
        }
    }
    {   // tail: slots hold steps 22,23; load 24 fresh
        const float4 te  = *(const float4*)(eb + (size_t)24 * V_);
        const float4 ta  = *(const float4*)(ab + (size_t)24 * V_);
        const float4 tw0 = *(const float4*)(wb + (size_t)24 * C_);
        const float4 tw1 = *(const float4*)(wb + (size_t)24 * C_ + 4);
        SSTEP(pe[0], pa[0], pw0[0], pw1[0]);
        SSTEP(pe[1], pa[1], pw0[1], pw1[1]);
        SSTEP(te, ta, tw0, tw1);
    }
    #undef SSTEP

    // store (D,U) as half2, layout du[chunk][b][v][c]
    __half2* dbase = du + ((size_t)(chunk * B_ + b) * (V_ * C_));
    #pragma unroll
    for (int i = 0; i < 4; ++i) {
        __half2 h[8];
        #pragma unroll
        for (int j = 0; j < 8; ++j)
            h[j] = __floats2half2_rn(Dm[i][j], ym[i][j]);
        __half2* dst = dbase + (v0 + i) * C_ + c0;
        *(uint4*)dst = *(const uint4*)&h[0];
        *(uint4*)(dst + 4) = *(const uint4*)&h[4];
    }
}

// ====== Combine + readout + phase3: 128 blocks x 256 thr ======
template<bool BF>
__device__ __forceinline__ void combine_body(
    const void* q_emb, const void* key_memory, const void* init_value_memory,
    const void* summ_W, const void* summ_b, const void* out_W, const void* out_b,
    const int* __restrict__ target_id, const __half2* __restrict__ du,
    void* outp, float* wtl, float* readl, float* summl)
{
    const int b = blockIdx.x;
    const int t = threadIdx.x;      // 0..255
    const long long qrow = (long long)target_id[b] * K_;

    // wt softmax (wave 0)
    if (t < 64) {
        float logit = 0.f;
        #pragma unroll 8
        for (int i = 0; i < K_; ++i)
            logit += ld<BF>(q_emb, qrow + i) * ld<BF>(key_memory, i * C_ + t);
        float m = logit;
        for (int off = 32; off > 0; off >>= 1)
            m = fmaxf(m, __shfl_xor(m, off, 64));
        const float ex = __expf(logit - m);
        float ssum = ex;
        for (int off = 32; off > 0; off >>= 1)
            ssum += __shfl_xor(ssum, off, 64);
        wtl[t] = ex / ssum;
    }

    // fold 8 chunks: thread (v = t>>1, c half = (t&1)*32), 32 c's
    const int v = t >> 1;
    const int c0 = (t & 1) * 32;
    float mem[32];
    #pragma unroll 8
    for (int k = 0; k < 32; ++k)
        mem[k] = ld<BF>(init_value_memory, v * C_ + c0 + k);
    #pragma unroll
    for (int ch = 0; ch < NCH; ++ch) {
        const __half2* dsrc = du + ((size_t)(ch * B_ + b) * (V_ * C_)) + v * C_ + c0;
        #pragma unroll
        for (int k = 0; k < 32; ++k) {
            const float2 f = __half22float2(dsrc[k]);
            mem[k] = fmaf(f.x, mem[k], f.y);   // mem = D*mem + U
        }
    }
    __syncthreads();   // wtl ready

    float pacc = 0.f;
    #pragma unroll
    for (int k = 0; k < 32; ++k)
        pacc += mem[k] * wtl[c0 + k];
    pacc += __shfl_xor(pacc, 1, 64);
    if ((t & 1) == 0) readl[v] = pacc;
    __syncthreads();

    // summ matvec + out
    if (t < 128) {
        float acc = ld<BF>(summ_b, t);
        #pragma unroll 8
        for (int i = 0; i < 128; ++i)
            acc += readl[i] * ld<BF>(summ_W, i * SUM_ + t);
        #pragma unroll 8
        for (int i = 0; i < 128; ++i)
            acc += ld<BF>(q_emb, qrow + i) * ld<BF>(summ_W, (128 + i) * SUM_ + t);
        summl[t] = fast_tanh(acc);
    }
    __syncthreads();
    if (t < 64) {
        float oacc = summl[t] * ld<BF>(out_W, t) + summl[t + 64] * ld<BF>(out_W, t + 64);
        for (int off = 32; off > 0; off >>= 1)
            oacc += __shfl_xor(oacc, off, 64);
        if (t == 0) {
            const float res = oacc + ld<BF>(out_b, 0);
            if (BF) ((__hip_bfloat16*)outp)[b] = __float2bfloat16(res);
            else    ((float*)outp)[b] = res;
        }
    }
}

__global__ __launch_bounds__(256) void dkvmn_combine(
    const void* q_emb, const void* key_memory, const void* init_value_memory,
    const void* summ_W, const void* summ_b, const void* out_W, const void* out_b,
    const void* erase_b, const int* __restrict__ target_id,
    const __half2* __restrict__ du, void* outp)
{
    __shared__ float wtl[C_], readl[V_], summl[SUM_];
    if (probe_flag_wave(erase_b))
        combine_body<true>(q_emb, key_memory, init_value_memory, summ_W, summ_b,
                           out_W, out_b, target_id, du, outp, wtl, readl, summl);
    else
        combine_body<false>(q_emb, key_memory, init_value_memory, summ_W, summ_b,
                            out_W, out_b, target_id, du, outp, wtl, readl, summl);
}

extern "C" void kernel_launch(void* const* d_in, const int* in_sizes, int n_in,
                              void* d_out, int out_size, void* d_ws, size_t ws_size,
                              hipStream_t stream) {
    const void* q_emb             = d_in[0];
    const void* i_emb             = d_in[1];
    const void* key_memory        = d_in[2];
    const void* init_value_memory = d_in[3];
    const void* erase_W           = d_in[4];
    const void* erase_b           = d_in[5];
    const void* add_W             = d_in[6];
    const void* add_b             = d_in[7];
    const void* summ_W            = d_in[8];
    const void* summ_b            = d_in[9];
    const void* out_W             = d_in[10];
    const void* out_b             = d_in[11];
    const int* input     = (const int*)d_in[12];
    const int* target_id = (const int*)d_in[13];

    // ws: e 13.1MB | a 13.1MB | w 6.6MB | wpack 80KB | du 33.5MB (fp16 pairs)
    float* e_buf = (float*)d_ws;
    float* a_buf = e_buf + (size_t)B_ * S_ * V_;
    float* w_buf = a_buf + (size_t)B_ * S_ * V_;
    unsigned short* wpack = (unsigned short*)(w_buf + (size_t)B_ * S_ * C_);
    __half2* du = (__half2*)(wpack + 5120 * 8);

    dkvmn_prepack<<<20, 256, 0, stream>>>(erase_W, add_W, key_memory, erase_b, wpack);
    dkvmn_phase1_mfma<<<(B_ * S_) / 64, 256, 0, stream>>>(
        q_emb, i_emb, erase_b, add_b, input, wpack, e_buf, a_buf, w_buf);
    dkvmn_scan<<<NCH * B_, 256, 0, stream>>>(e_buf, a_buf, w_buf, du);
    dkvmn_combine<<<B_, 256, 0, stream>>>(
        q_emb, key_memory, init_value_memory, summ_W, summ_b, out_W, out_b,
        erase_b, target_id, du, d_out);
}

// Round 12
// 148.040 us; speedup vs baseline: 1.1146x; 1.0442x over previous
//
#include <hip/hip_runtime.h>
#include <hip/hip_bf16.h>
#include <hip/hip_fp16.h>

#define B_ 128
#define S_ 200
#define QN_ 20000
#define V_ 128
#define K_ 128
#define C_ 64
#define SUM_ 128
#define NCH 8           // scan chunks (S = 8 * 25)
#define CL 25           // steps per chunk

using short8 = __attribute__((ext_vector_type(8))) short;
using f32x4  = __attribute__((ext_vector_type(4))) float;

__device__ __forceinline__ float fast_sigmoid(float x) { return 1.f / (1.f + __expf(-x)); }
__device__ __forceinline__ float fast_tanh(float x)    { return 1.f - 2.f / (__expf(2.f * x) + 1.f); }

template<bool BF>
__device__ __forceinline__ float ld(const void* p, long long i) {
    if (BF) return __bfloat162float(((const __hip_bfloat16*)p)[i]);
    return ((const float*)p)[i];
}

__device__ __forceinline__ unsigned short f2bf(float v) {
    __hip_bfloat16 h = __float2bfloat16(v);
    unsigned short u;
    __builtin_memcpy(&u, &h, 2);
    return u;
}

__device__ __forceinline__ void ld4h(const __half* p, float* out) {
    const float2 f01 = __half22float2(*(const __half2*)p);
    const float2 f23 = __half22float2(*(const __half2*)(p + 2));
    out[0] = f01.x; out[1] = f01.y; out[2] = f23.x; out[3] = f23.y;
}

__device__ __forceinline__ int probe_flag_wave(const void* erase_b) {
    const unsigned* w = (const unsigned*)erase_b;
    const int lane = threadIdx.x & 63;
    const unsigned lo = w[lane] & 0xffffu;
    const float f = __uint_as_float(lo << 16);
    const unsigned long long bal = __ballot(!(fabsf(f) <= 0.5f));
    return (__popcll(bal) <= 8) ? 1 : 0;  // 1 = bf16
}

// ============ Prepack: weights -> bf16 MFMA B-fragments (80 KB) ============
__global__ __launch_bounds__(256) void dkvmn_prepack(
    const void* erase_W, const void* add_W, const void* key_memory,
    const void* erase_b, unsigned short* __restrict__ wpack)
{
    const int bf = probe_flag_wave(erase_b);
    const int fid = blockIdx.x * 256 + threadIdx.x;  // 0..5119
    if (fid >= 5120) return;
    const int lane = fid & 63;
    const int ks = (fid >> 6) & 3;
    const int wv = (fid >> 8) & 3;
    const int q  = fid >> 10;
    const int nt = wv + 4 * q;
    const void* Wsrc;
    int ncol, ldn;
    if (q < 2)      { Wsrc = erase_W;    ncol = nt * 16 + (lane & 15);        ldn = 128; }
    else if (q < 4) { Wsrc = add_W;      ncol = (nt - 8) * 16 + (lane & 15);  ldn = 128; }
    else            { Wsrc = key_memory; ncol = (nt - 16) * 16 + (lane & 15); ldn = 64; }
    const int k8 = (lane >> 4) * 8;
    unsigned short o[8];
    #pragma unroll
    for (int jj = 0; jj < 8; ++jj) {
        const long long idx = (long long)(ks * 32 + k8 + jj) * ldn + ncol;
        const float v = bf ? ld<true>(Wsrc, idx) : ld<false>(Wsrc, idx);
        o[jj] = f2bf(v);
    }
    *(uint4*)(wpack + (size_t)fid * 8) = *(const uint4*)o;
}

// ============ Fused phase1+scan: 1024 blocks (b, chunk), 256 threads ============
// MFMA computes e/a/w for the block's 25 positions into LDS; the affine scan
// composes them into (D, U) per (v,c) element and stores fp16 to du.
struct FusedLDS {
    unsigned short ivA[32 * 136];   // bf16 A rows (25 real + 7 dup)
    unsigned short qvA[32 * 136];
    __half esh[32 * 136];           // e, fp16
    __half ash[32 * 136];           // a, fp16
    float  wlog[32 * 68];           // logits then probs
    int sidx[32], sqid[32];
};

template<bool BF>
__device__ __forceinline__ void fused_body(
    const void* q_emb, const void* i_emb,
    const void* erase_b, const void* add_b,
    const int* __restrict__ input, const unsigned short* __restrict__ wpack,
    __half2* __restrict__ du, FusedLDS& sm)
{
    const int bid = blockIdx.x;
    const int b = bid & 127;            // XCD affinity: all chunks of b on b%8
    const int chunk = bid >> 7;         // 0..7
    const int t = threadIdx.x;          // 0..255
    const int wv = t >> 6;
    const int lane = t & 63;
    const int lrow = lane & 15;
    const int lk8 = (lane >> 4) * 8;

    if (t < 32) {
        const int s = (t < CL) ? t : 0;
        const int ix = input[b * S_ + chunk * CL + s];
        sm.sidx[t] = ix;
        sm.sqid[t] = ix > QN_ ? ix - QN_ : ix;
    }
    __syncthreads();

    // stage A: 2 tensors x 32 rows x 16 segs of 8 elems (fp32->bf16 convert)
    #pragma unroll
    for (int r = 0; r < 4; ++r) {
        const int j = t + 256 * r;      // 0..1023
        const int tensor = j >> 9;
        const int row = (j >> 4) & 31;
        const int seg = j & 15;
        const int gr = tensor ? sm.sqid[row] : sm.sidx[row];
        unsigned short* dst = (tensor ? sm.qvA : sm.ivA) + row * 136 + seg * 8;
        if (BF) {
            const unsigned short* src = (const unsigned short*)(tensor ? q_emb : i_emb);
            *(uint4*)dst = *(const uint4*)(src + (long long)gr * 128 + seg * 8);
        } else {
            const float* src = (const float*)(tensor ? q_emb : i_emb) + (long long)gr * 128 + seg * 8;
            const float4 f0 = *(const float4*)src;
            const float4 f1 = *(const float4*)(src + 4);
            unsigned short o[8] = {f2bf(f0.x), f2bf(f0.y), f2bf(f0.z), f2bf(f0.w),
                                   f2bf(f1.x), f2bf(f1.y), f2bf(f1.z), f2bf(f1.w)};
            *(uint4*)dst = *(const uint4*)o;
        }
    }

    // B fragments from prepacked buffer (L2-resident)
    short8 bfr[5][4];
    int nco[5];
    float biasq[4];
    #pragma unroll
    for (int q = 0; q < 5; ++q) {
        const int nt = wv + 4 * q;
        if (q < 2)      nco[q] = nt * 16 + lrow;
        else if (q < 4) nco[q] = (nt - 8) * 16 + lrow;
        else            nco[q] = (nt - 16) * 16 + lrow;
        if (q < 2)      biasq[q] = ld<BF>(erase_b, nco[q]);
        else if (q < 4) biasq[q] = ld<BF>(add_b, nco[q]);
        #pragma unroll
        for (int ks = 0; ks < 4; ++ks)
            bfr[q][ks] = *(const short8*)(wpack +
                ((size_t)(((q * 4 + wv) * 4 + ks) * 64 + lane)) * 8);
    }
    __syncthreads();

    // IV tiles: erase (q=0,1), add (q=2,3) -> LDS fp16
    #pragma unroll
    for (int mt = 0; mt < 2; ++mt) {
        short8 afr[4];
        const unsigned short* ar = sm.ivA + (mt * 16 + lrow) * 136 + lk8;
        #pragma unroll
        for (int ks = 0; ks < 4; ++ks)
            afr[ks] = *(const short8*)(ar + ks * 32);
        #pragma unroll
        for (int q = 0; q < 4; ++q) {
            f32x4 acc = {0.f, 0.f, 0.f, 0.f};
            #pragma unroll
            for (int ks = 0; ks < 4; ++ks)
                acc = __builtin_amdgcn_mfma_f32_16x16x32_bf16(afr[ks], bfr[q][ks], acc, 0, 0, 0);
            const int ncol = nco[q];
            const float bb = biasq[q];
            #pragma unroll
            for (int r = 0; r < 4; ++r) {
                const int orow = mt * 16 + (lane >> 4) * 4 + r;
                const float y = acc[r] + bb;
                if (q < 2) sm.esh[orow * 136 + ncol] = __float2half(fast_sigmoid(y));
                else       sm.ash[orow * 136 + ncol] = __float2half(fast_tanh(y));
            }
        }
    }
    // QV key tiles (q=4): logits -> LDS
    #pragma unroll
    for (int mt = 0; mt < 2; ++mt) {
        short8 afr[4];
        const unsigned short* ar = sm.qvA + (mt * 16 + lrow) * 136 + lk8;
        #pragma unroll
        for (int ks = 0; ks < 4; ++ks)
            afr[ks] = *(const short8*)(ar + ks * 32);
        f32x4 acc = {0.f, 0.f, 0.f, 0.f};
        #pragma unroll
        for (int ks = 0; ks < 4; ++ks)
            acc = __builtin_amdgcn_mfma_f32_16x16x32_bf16(afr[ks], bfr[4][ks], acc, 0, 0, 0);
        #pragma unroll
        for (int r = 0; r < 4; ++r)
            sm.wlog[(mt * 16 + (lane >> 4) * 4 + r) * 68 + nco[4]] = acc[r];
    }
    __syncthreads();

    // softmax in place: row = t>>3 (0..31), 8-col segment cs = t&7
    {
        const int row = t >> 3;
        const int cs = t & 7;
        float* wr = &sm.wlog[row * 68 + cs * 8];
        float v[8];
        *(float4*)&v[0] = *(const float4*)&wr[0];
        *(float4*)&v[4] = *(const float4*)&wr[4];
        float m = v[0];
        #pragma unroll
        for (int ii = 1; ii < 8; ++ii) m = fmaxf(m, v[ii]);
        m = fmaxf(m, __shfl_xor(m, 1, 64));
        m = fmaxf(m, __shfl_xor(m, 2, 64));
        m = fmaxf(m, __shfl_xor(m, 4, 64));
        float s = 0.f;
        #pragma unroll
        for (int ii = 0; ii < 8; ++ii) { v[ii] = __expf(v[ii] - m); s += v[ii]; }
        s += __shfl_xor(s, 1, 64);
        s += __shfl_xor(s, 2, 64);
        s += __shfl_xor(s, 4, 64);
        const float inv = 1.f / s;
        *(float4*)&wr[0] = make_float4(v[0]*inv, v[1]*inv, v[2]*inv, v[3]*inv);
        *(float4*)&wr[4] = make_float4(v[4]*inv, v[5]*inv, v[6]*inv, v[7]*inv);
    }
    __syncthreads();

    // affine scan over 25 steps from LDS; thread tile 4v x 8c
    const int vg = t >> 3;          // 0..31
    const int cg = t & 7;           // 0..7
    const int v0 = vg * 4, c0 = cg * 8;

    float ym[4][8], Dm[4][8];
    #pragma unroll
    for (int i = 0; i < 4; ++i)
        #pragma unroll
        for (int j = 0; j < 8; ++j) { ym[i][j] = 0.f; Dm[i][j] = 1.f; }

    for (int s = 0; s < CL; ++s) {
        float ev[4], av[4], wv8[8];
        ld4h(sm.esh + s * 136 + v0, ev);
        ld4h(sm.ash + s * 136 + v0, av);
        *(float4*)&wv8[0] = *(const float4*)(sm.wlog + s * 68 + c0);
        *(float4*)&wv8[4] = *(const float4*)(sm.wlog + s * 68 + c0 + 4);
        #pragma unroll
        for (int i = 0; i < 4; ++i) {
            #pragma unroll
            for (int j = 0; j < 8; ++j) {
                const float d = fmaf(-ev[i], wv8[j], 1.f);
                Dm[i][j] *= d;
                ym[i][j] = fmaf(d, ym[i][j], av[i] * wv8[j]);
            }
        }
    }

    // store (D,U) as half2, layout du[chunk][b][v][c]
    __half2* dbase = du + ((size_t)(chunk * B_ + b) * (V_ * C_));
    #pragma unroll
    for (int i = 0; i < 4; ++i) {
        __half2 h[8];
        #pragma unroll
        for (int j = 0; j < 8; ++j)
            h[j] = __floats2half2_rn(Dm[i][j], ym[i][j]);
        __half2* dst = dbase + (v0 + i) * C_ + c0;
        *(uint4*)dst = *(const uint4*)&h[0];
        *(uint4*)(dst + 4) = *(const uint4*)&h[4];
    }
}

__global__ __launch_bounds__(256) void dkvmn_fused(
    const void* q_emb, const void* i_emb,
    const void* erase_b, const void* add_b,
    const int* __restrict__ input, const unsigned short* __restrict__ wpack,
    __half2* __restrict__ du)
{
    __shared__ FusedLDS sm;
    if (probe_flag_wave(erase_b))
        fused_body<true>(q_emb, i_emb, erase_b, add_b, input, wpack, du, sm);
    else
        fused_body<false>(q_emb, i_emb, erase_b, add_b, input, wpack, du, sm);
}

// ====== Combine + readout + summ/out: 128 blocks x 256 thr (r11, unchanged) ======
template<bool BF>
__device__ __forceinline__ void combine_body(
    const void* q_emb, const void* key_memory, const void* init_value_memory,
    const void* summ_W, const void* summ_b, const void* out_W, const void* out_b,
    const int* __restrict__ target_id, const __half2* __restrict__ du,
    void* outp, float* wtl, float* readl, float* summl)
{
    const int b = blockIdx.x;
    const int t = threadIdx.x;      // 0..255
    const long long qrow = (long long)target_id[b] * K_;

    if (t < 64) {
        float logit = 0.f;
        #pragma unroll 8
        for (int i = 0; i < K_; ++i)
            logit += ld<BF>(q_emb, qrow + i) * ld<BF>(key_memory, i * C_ + t);
        float m = logit;
        for (int off = 32; off > 0; off >>= 1)
            m = fmaxf(m, __shfl_xor(m, off, 64));
        const float ex = __expf(logit - m);
        float ssum = ex;
        for (int off = 32; off > 0; off >>= 1)
            ssum += __shfl_xor(ssum, off, 64);
        wtl[t] = ex / ssum;
    }

    const int v = t >> 1;
    const int c0 = (t & 1) * 32;
    float mem[32];
    #pragma unroll 8
    for (int k = 0; k < 32; ++k)
        mem[k] = ld<BF>(init_value_memory, v * C_ + c0 + k);
    #pragma unroll
    for (int ch = 0; ch < NCH; ++ch) {
        const __half2* dsrc = du + ((size_t)(ch * B_ + b) * (V_ * C_)) + v * C_ + c0;
        #pragma unroll
        for (int k = 0; k < 32; ++k) {
            const float2 f = __half22float2(dsrc[k]);
            mem[k] = fmaf(f.x, mem[k], f.y);   // mem = D*mem + U
        }
    }
    __syncthreads();

    float pacc = 0.f;
    #pragma unroll
    for (int k = 0; k < 32; ++k)
        pacc += mem[k] * wtl[c0 + k];
    pacc += __shfl_xor(pacc, 1, 64);
    if ((t & 1) == 0) readl[v] = pacc;
    __syncthreads();

    if (t < 128) {
        float acc = ld<BF>(summ_b, t);
        #pragma unroll 8
        for (int i = 0; i < 128; ++i)
            acc += readl[i] * ld<BF>(summ_W, i * SUM_ + t);
        #pragma unroll 8
        for (int i = 0; i < 128; ++i)
            acc += ld<BF>(q_emb, qrow + i) * ld<BF>(summ_W, (128 + i) * SUM_ + t);
        summl[t] = fast_tanh(acc);
    }
    __syncthreads();
    if (t < 64) {
        float oacc = summl[t] * ld<BF>(out_W, t) + summl[t + 64] * ld<BF>(out_W, t + 64);
        for (int off = 32; off > 0; off >>= 1)
            oacc += __shfl_xor(oacc, off, 64);
        if (t == 0) {
            const float res = oacc + ld<BF>(out_b, 0);
            if (BF) ((__hip_bfloat16*)outp)[b] = __float2bfloat16(res);
            else    ((float*)outp)[b] = res;
        }
    }
}

__global__ __launch_bounds__(256) void dkvmn_combine(
    const void* q_emb, const void* key_memory, const void* init_value_memory,
    const void* summ_W, const void* summ_b, const void* out_W, const void* out_b,
    const void* erase_b, const int* __restrict__ target_id,
    const __half2* __restrict__ du, void* outp)
{
    __shared__ float wtl[C_], readl[V_], summl[SUM_];
    if (probe_flag_wave(erase_b))
        combine_body<true>(q_emb, key_memory, init_value_memory, summ_W, summ_b,
                           out_W, out_b, target_id, du, outp, wtl, readl, summl);
    else
        combine_body<false>(q_emb, key_memory, init_value_memory, summ_W, summ_b,
                            out_W, out_b, target_id, du, outp, wtl, readl, summl);
}

extern "C" void kernel_launch(void* const* d_in, const int* in_sizes, int n_in,
                              void* d_out, int out_size, void* d_ws, size_t ws_size,
                              hipStream_t stream) {
    const void* q_emb             = d_in[0];
    const void* i_emb             = d_in[1];
    const void* key_memory        = d_in[2];
    const void* init_value_memory = d_in[3];
    const void* erase_W           = d_in[4];
    const void* erase_b           = d_in[5];
    const void* add_W             = d_in[6];
    const void* add_b             = d_in[7];
    const void* summ_W            = d_in[8];
    const void* summ_b            = d_in[9];
    const void* out_W             = d_in[10];
    const void* out_b             = d_in[11];
    const int* input     = (const int*)d_in[12];
    const int* target_id = (const int*)d_in[13];

    // ws: wpack 80KB | du 33.5MB (fp16 (D,U) pairs)
    unsigned short* wpack = (unsigned short*)d_ws;
    __half2* du = (__half2*)(wpack + 5120 * 8);

    dkvmn_prepack<<<20, 256, 0, stream>>>(erase_W, add_W, key_memory, erase_b, wpack);
    dkvmn_fused<<<NCH * B_, 256, 0, stream>>>(
        q_emb, i_emb, erase_b, add_b, input, wpack, du);
    dkvmn_combine<<<B_, 256, 0, stream>>>(
        q_emb, key_memory, init_value_memory, summ_W, summ_b, out_W, out_b,
        erase_b, target_id, du, d_out);
}

// Round 14
// 147.163 us; speedup vs baseline: 1.1212x; 1.0060x over previous
//
#include <hip/hip_runtime.h>
#include <hip/hip_bf16.h>
#include <hip/hip_fp16.h>

#define B_ 128
#define S_ 200
#define QN_ 20000
#define V_ 128
#define K_ 128
#define C_ 64
#define SUM_ 128
#define NCH 8           // scan chunks (S = 8 * 25)
#define CL 25           // steps per chunk

using short8 = __attribute__((ext_vector_type(8))) short;
using f32x4  = __attribute__((ext_vector_type(4))) float;

__device__ __forceinline__ float fast_sigmoid(float x) { return 1.f / (1.f + __expf(-x)); }
__device__ __forceinline__ float fast_tanh(float x)    { return 1.f - 2.f / (__expf(2.f * x) + 1.f); }

template<bool BF>
__device__ __forceinline__ float ld(const void* p, long long i) {
    if (BF) return __bfloat162float(((const __hip_bfloat16*)p)[i]);
    return ((const float*)p)[i];
}

__device__ __forceinline__ unsigned short f2bf(float v) {
    __hip_bfloat16 h = __float2bfloat16(v);
    unsigned short u;
    __builtin_memcpy(&u, &h, 2);
    return u;
}

__device__ __forceinline__ void ld4h(const __half* p, float* out) {
    const float2 f01 = __half22float2(*(const __half2*)p);
    const float2 f23 = __half22float2(*(const __half2*)(p + 2));
    out[0] = f01.x; out[1] = f01.y; out[2] = f23.x; out[3] = f23.y;
}

__device__ __forceinline__ int probe_flag_wave(const void* erase_b) {
    const unsigned* w = (const unsigned*)erase_b;
    const int lane = threadIdx.x & 63;
    const unsigned lo = w[lane] & 0xffffu;
    const float f = __uint_as_float(lo << 16);
    const unsigned long long bal = __ballot(!(fabsf(f) <= 0.5f));
    return (__popcll(bal) <= 8) ? 1 : 0;  // 1 = bf16
}

// ===== Prepack (blocks 0..19) + wt softmax (blocks 20..147, one per batch) =====
template<bool BF>
__device__ __forceinline__ void wt_body(
    const void* q_emb, const void* key_memory, const int* __restrict__ target_id,
    int b, float* __restrict__ wt_buf)
{
    const int t = threadIdx.x;
    if (t >= 64) return;
    const long long qrow = (long long)target_id[b] * K_;
    float logit = 0.f;
    #pragma unroll 8
    for (int i = 0; i < K_; ++i)
        logit += ld<BF>(q_emb, qrow + i) * ld<BF>(key_memory, i * C_ + t);
    float m = logit;
    for (int off = 32; off > 0; off >>= 1)
        m = fmaxf(m, __shfl_xor(m, off, 64));
    const float ex = __expf(logit - m);
    float ssum = ex;
    for (int off = 32; off > 0; off >>= 1)
        ssum += __shfl_xor(ssum, off, 64);
    wt_buf[b * C_ + t] = ex / ssum;
}

__global__ __launch_bounds__(256) void dkvmn_prepack(
    const void* erase_W, const void* add_W, const void* key_memory,
    const void* erase_b, const void* q_emb, const int* __restrict__ target_id,
    unsigned short* __restrict__ wpack, float* __restrict__ wt_buf)
{
    const int bf = probe_flag_wave(erase_b);
    if (blockIdx.x >= 20) {
        const int b = blockIdx.x - 20;
        if (bf) wt_body<true>(q_emb, key_memory, target_id, b, wt_buf);
        else    wt_body<false>(q_emb, key_memory, target_id, b, wt_buf);
        return;
    }
    const int fid = blockIdx.x * 256 + threadIdx.x;  // 0..5119
    if (fid >= 5120) return;
    const int lane = fid & 63;
    const int ks = (fid >> 6) & 3;
    const int wv = (fid >> 8) & 3;
    const int q  = fid >> 10;
    const int nt = wv + 4 * q;
    const void* Wsrc;
    int ncol, ldn;
    if (q < 2)      { Wsrc = erase_W;    ncol = nt * 16 + (lane & 15);        ldn = 128; }
    else if (q < 4) { Wsrc = add_W;      ncol = (nt - 8) * 16 + (lane & 15);  ldn = 128; }
    else            { Wsrc = key_memory; ncol = (nt - 16) * 16 + (lane & 15); ldn = 64; }
    const int k8 = (lane >> 4) * 8;
    unsigned short o[8];
    #pragma unroll
    for (int jj = 0; jj < 8; ++jj) {
        const long long idx = (long long)(ks * 32 + k8 + jj) * ldn + ncol;
        const float v = bf ? ld<true>(Wsrc, idx) : ld<false>(Wsrc, idx);
        o[jj] = f2bf(v);
    }
    *(uint4*)(wpack + (size_t)fid * 8) = *(const uint4*)o;
}

// ============ Fused phase1+scan: 1024 blocks (b, chunk), 256 threads ============
struct FusedLDS {
    unsigned short ivA[32 * 136];
    unsigned short qvA[32 * 136];
    __half esh[32 * 136];
    __half ash[32 * 136];
    float  wlog[32 * 68];
    int sidx[32], sqid[32];
};

template<bool BF>
__device__ __forceinline__ void fused_body(
    const void* q_emb, const void* i_emb,
    const void* erase_b, const void* add_b,
    const int* __restrict__ input, const unsigned short* __restrict__ wpack,
    __half2* __restrict__ du, FusedLDS& sm)
{
    const int bid = blockIdx.x;
    const int b = bid & 127;            // XCD affinity: all chunks of b on b%8
    const int chunk = bid >> 7;         // 0..7
    const int t = threadIdx.x;          // 0..255
    const int wv = t >> 6;
    const int lane = t & 63;
    const int lrow = lane & 15;
    const int lk8 = (lane >> 4) * 8;

    if (t < 32) {
        const int s = (t < CL) ? t : 0;
        const int ix = input[b * S_ + chunk * CL + s];
        sm.sidx[t] = ix;
        sm.sqid[t] = ix > QN_ ? ix - QN_ : ix;
    }
    __syncthreads();

    #pragma unroll
    for (int r = 0; r < 4; ++r) {
        const int j = t + 256 * r;      // 0..1023
        const int tensor = j >> 9;
        const int row = (j >> 4) & 31;
        const int seg = j & 15;
        const int gr = tensor ? sm.sqid[row] : sm.sidx[row];
        unsigned short* dst = (tensor ? sm.qvA : sm.ivA) + row * 136 + seg * 8;
        if (BF) {
            const unsigned short* src = (const unsigned short*)(tensor ? q_emb : i_emb);
            *(uint4*)dst = *(const uint4*)(src + (long long)gr * 128 + seg * 8);
        } else {
            const float* src = (const float*)(tensor ? q_emb : i_emb) + (long long)gr * 128 + seg * 8;
            const float4 f0 = *(const float4*)src;
            const float4 f1 = *(const float4*)(src + 4);
            unsigned short o[8] = {f2bf(f0.x), f2bf(f0.y), f2bf(f0.z), f2bf(f0.w),
                                   f2bf(f1.x), f2bf(f1.y), f2bf(f1.z), f2bf(f1.w)};
            *(uint4*)dst = *(const uint4*)o;
        }
    }

    short8 bfr[5][4];
    int nco[5];
    float biasq[4];
    #pragma unroll
    for (int q = 0; q < 5; ++q) {
        const int nt = wv + 4 * q;
        if (q < 2)      nco[q] = nt * 16 + lrow;
        else if (q < 4) nco[q] = (nt - 8) * 16 + lrow;
        else            nco[q] = (nt - 16) * 16 + lrow;
        if (q < 2)      biasq[q] = ld<BF>(erase_b, nco[q]);
        else if (q < 4) biasq[q] = ld<BF>(add_b, nco[q]);
        #pragma unroll
        for (int ks = 0; ks < 4; ++ks)
            bfr[q][ks] = *(const short8*)(wpack +
                ((size_t)(((q * 4 + wv) * 4 + ks) * 64 + lane)) * 8);
    }
    __syncthreads();

    #pragma unroll
    for (int mt = 0; mt < 2; ++mt) {
        short8 afr[4];
        const unsigned short* ar = sm.ivA + (mt * 16 + lrow) * 136 + lk8;
        #pragma unroll
        for (int ks = 0; ks < 4; ++ks)
            afr[ks] = *(const short8*)(ar + ks * 32);
        #pragma unroll
        for (int q = 0; q < 4; ++q) {
            f32x4 acc = {0.f, 0.f, 0.f, 0.f};
            #pragma unroll
            for (int ks = 0; ks < 4; ++ks)
                acc = __builtin_amdgcn_mfma_f32_16x16x32_bf16(afr[ks], bfr[q][ks], acc, 0, 0, 0);
            const int ncol = nco[q];
            const float bb = biasq[q];
            #pragma unroll
            for (int r = 0; r < 4; ++r) {
                const int orow = mt * 16 + (lane >> 4) * 4 + r;
                const float y = acc[r] + bb;
                if (q < 2) sm.esh[orow * 136 + ncol] = __float2half(fast_sigmoid(y));
                else       sm.ash[orow * 136 + ncol] = __float2half(fast_tanh(y));
            }
        }
    }
    #pragma unroll
    for (int mt = 0; mt < 2; ++mt) {
        short8 afr[4];
        const unsigned short* ar = sm.qvA + (mt * 16 + lrow) * 136 + lk8;
        #pragma unroll
        for (int ks = 0; ks < 4; ++ks)
            afr[ks] = *(const short8*)(ar + ks * 32);
        f32x4 acc = {0.f, 0.f, 0.f, 0.f};
        #pragma unroll
        for (int ks = 0; ks < 4; ++ks)
            acc = __builtin_amdgcn_mfma_f32_16x16x32_bf16(afr[ks], bfr[4][ks], acc, 0, 0, 0);
        #pragma unroll
        for (int r = 0; r < 4; ++r)
            sm.wlog[(mt * 16 + (lane >> 4) * 4 + r) * 68 + nco[4]] = acc[r];
    }
    __syncthreads();

    {
        const int row = t >> 3;
        const int cs = t & 7;
        float* wr = &sm.wlog[row * 68 + cs * 8];
        float v[8];
        *(float4*)&v[0] = *(const float4*)&wr[0];
        *(float4*)&v[4] = *(const float4*)&wr[4];
        float m = v[0];
        #pragma unroll
        for (int ii = 1; ii < 8; ++ii) m = fmaxf(m, v[ii]);
        m = fmaxf(m, __shfl_xor(m, 1, 64));
        m = fmaxf(m, __shfl_xor(m, 2, 64));
        m = fmaxf(m, __shfl_xor(m, 4, 64));
        float s = 0.f;
        #pragma unroll
        for (int ii = 0; ii < 8; ++ii) { v[ii] = __expf(v[ii] - m); s += v[ii]; }
        s += __shfl_xor(s, 1, 64);
        s += __shfl_xor(s, 2, 64);
        s += __shfl_xor(s, 4, 64);
        const float inv = 1.f / s;
        *(float4*)&wr[0] = make_float4(v[0]*inv, v[1]*inv, v[2]*inv, v[3]*inv);
        *(float4*)&wr[4] = make_float4(v[4]*inv, v[5]*inv, v[6]*inv, v[7]*inv);
    }
    __syncthreads();

    const int vg = t >> 3;
    const int cg = t & 7;
    const int v0 = vg * 4, c0 = cg * 8;

    float ym[4][8], Dm[4][8];
    #pragma unroll
    for (int i = 0; i < 4; ++i)
        #pragma unroll
        for (int j = 0; j < 8; ++j) { ym[i][j] = 0.f; Dm[i][j] = 1.f; }

    for (int s = 0; s < CL; ++s) {
        float ev[4], av[4], wv8[8];
        ld4h(sm.esh + s * 136 + v0, ev);
        ld4h(sm.ash + s * 136 + v0, av);
        *(float4*)&wv8[0] = *(const float4*)(sm.wlog + s * 68 + c0);
        *(float4*)&wv8[4] = *(const float4*)(sm.wlog + s * 68 + c0 + 4);
        #pragma unroll
        for (int i = 0; i < 4; ++i) {
            #pragma unroll
            for (int j = 0; j < 8; ++j) {
                const float d = fmaf(-ev[i], wv8[j], 1.f);
                Dm[i][j] *= d;
                ym[i][j] = fmaf(d, ym[i][j], av[i] * wv8[j]);
            }
        }
    }

    __half2* dbase = du + ((size_t)(chunk * B_ + b) * (V_ * C_));
    #pragma unroll
    for (int i = 0; i < 4; ++i) {
        __half2 h[8];
        #pragma unroll
        for (int j = 0; j < 8; ++j)
            h[j] = __floats2half2_rn(Dm[i][j], ym[i][j]);
        __half2* dst = dbase + (v0 + i) * C_ + c0;
        *(uint4*)dst = *(const uint4*)&h[0];
        *(uint4*)(dst + 4) = *(const uint4*)&h[4];
    }
}

__global__ __launch_bounds__(256) void dkvmn_fused(
    const void* q_emb, const void* i_emb,
    const void* erase_b, const void* add_b,
    const int* __restrict__ input, const unsigned short* __restrict__ wpack,
    __half2* __restrict__ du)
{
    __shared__ FusedLDS sm;
    if (probe_flag_wave(erase_b))
        fused_body<true>(q_emb, i_emb, erase_b, add_b, input, wpack, du, sm);
    else
        fused_body<false>(q_emb, i_emb, erase_b, add_b, input, wpack, du, sm);
}

// ====== Fold: 512 blocks (4 v-quarters x 128 b) x 256 thr; all-chunks-in-flight ======
template<bool BF>
__device__ __forceinline__ void fold_body(
    const void* init_value_memory, const __half2* __restrict__ du,
    const float* __restrict__ wt_buf, float* __restrict__ readl_buf)
{
    const int bid = blockIdx.x;
    const int b = bid & 127;          // XCD: bid%8 == b%8 -> du L2-local
    const int sub = bid >> 7;         // 0..3
    const int t = threadIdx.x;        // 0..255
    const int v = sub * 32 + (t >> 3);
    const int cg = t & 7;
    const int c0 = cg * 8;            // 8 c's = 8 half2 = 32 B per chunk

    // issue all 16 independent 16-B loads together (vmcnt-pipelined)
    // FIX vs r13: 8 half2 = 32 B needs TWO uint4 per chunk (r13 read 16 B and
    // ran off the end of the register array -> wrong c4..c7 folds).
    uint4 qa[NCH], qb[NCH];
    #pragma unroll
    for (int ch = 0; ch < NCH; ++ch) {
        const __half2* base = du + ((size_t)(ch * B_ + b) * (V_ * C_)) + v * C_ + c0;
        qa[ch] = *(const uint4*)base;         // c0..c0+3
        qb[ch] = *(const uint4*)(base + 4);   // c0+4..c0+7
    }

    float mem[8];
    #pragma unroll
    for (int k = 0; k < 8; ++k)
        mem[k] = ld<BF>(init_value_memory, v * C_ + c0 + k);

    #pragma unroll
    for (int ch = 0; ch < NCH; ++ch) {
        const __half2* hA = (const __half2*)&qa[ch];
        const __half2* hB = (const __half2*)&qb[ch];
        #pragma unroll
        for (int k = 0; k < 4; ++k) {
            const float2 fA = __half22float2(hA[k]);   // (D, U) for c0+k
            mem[k] = fmaf(fA.x, mem[k], fA.y);
            const float2 fB = __half22float2(hB[k]);   // (D, U) for c0+4+k
            mem[4 + k] = fmaf(fB.x, mem[4 + k], fB.y);
        }
    }

    float wt8[8];
    *(float4*)&wt8[0] = *(const float4*)(wt_buf + b * C_ + c0);
    *(float4*)&wt8[4] = *(const float4*)(wt_buf + b * C_ + c0 + 4);
    float pacc = 0.f;
    #pragma unroll
    for (int k = 0; k < 8; ++k) pacc += mem[k] * wt8[k];
    pacc += __shfl_xor(pacc, 1, 64);
    pacc += __shfl_xor(pacc, 2, 64);
    pacc += __shfl_xor(pacc, 4, 64);
    if (cg == 0) readl_buf[b * V_ + v] = pacc;
}

__global__ __launch_bounds__(256) void dkvmn_fold(
    const void* init_value_memory, const void* erase_b,
    const __half2* __restrict__ du, const float* __restrict__ wt_buf,
    float* __restrict__ readl_buf)
{
    if (probe_flag_wave(erase_b))
        fold_body<true>(init_value_memory, du, wt_buf, readl_buf);
    else
        fold_body<false>(init_value_memory, du, wt_buf, readl_buf);
}

// ============ Final: summ matvec + out; 128 blocks x 128 thr ============
template<bool BF>
__device__ __forceinline__ void final_body(
    const void* q_emb, const void* summ_W, const void* summ_b,
    const void* out_W, const void* out_b,
    const int* __restrict__ target_id, const float* __restrict__ readl_buf,
    void* outp, float* readl, float* summl)
{
    const int b = blockIdx.x;
    const int t = threadIdx.x;  // 0..127
    const long long qrow = (long long)target_id[b] * K_;

    readl[t] = readl_buf[b * V_ + t];
    __syncthreads();

    float acc = ld<BF>(summ_b, t);
    #pragma unroll 8
    for (int i = 0; i < 128; ++i)
        acc += readl[i] * ld<BF>(summ_W, i * SUM_ + t);
    #pragma unroll 8
    for (int i = 0; i < 128; ++i)
        acc += ld<BF>(q_emb, qrow + i) * ld<BF>(summ_W, (128 + i) * SUM_ + t);
    summl[t] = fast_tanh(acc);
    __syncthreads();

    if (t < 64) {
        float oacc = summl[t] * ld<BF>(out_W, t) + summl[t + 64] * ld<BF>(out_W, t + 64);
        for (int off = 32; off > 0; off >>= 1)
            oacc += __shfl_xor(oacc, off, 64);
        if (t == 0) {
            const float res = oacc + ld<BF>(out_b, 0);
            if (BF) ((__hip_bfloat16*)outp)[b] = __float2bfloat16(res);
            else    ((float*)outp)[b] = res;
        }
    }
}

__global__ __launch_bounds__(128) void dkvmn_final(
    const void* q_emb, const void* summ_W, const void* summ_b,
    const void* out_W, const void* out_b, const void* erase_b,
    const int* __restrict__ target_id, const float* __restrict__ readl_buf,
    void* outp)
{
    __shared__ float readl[V_], summl[SUM_];
    if (probe_flag_wave(erase_b))
        final_body<true>(q_emb, summ_W, summ_b, out_W, out_b, target_id,
                         readl_buf, outp, readl, summl);
    else
        final_body<false>(q_emb, summ_W, summ_b, out_W, out_b, target_id,
                          readl_buf, outp, readl, summl);
}

extern "C" void kernel_launch(void* const* d_in, const int* in_sizes, int n_in,
                              void* d_out, int out_size, void* d_ws, size_t ws_size,
                              hipStream_t stream) {
    const void* q_emb             = d_in[0];
    const void* i_emb             = d_in[1];
    const void* key_memory        = d_in[2];
    const void* init_value_memory = d_in[3];
    const void* erase_W           = d_in[4];
    const void* erase_b           = d_in[5];
    const void* add_W             = d_in[6];
    const void* add_b             = d_in[7];
    const void* summ_W            = d_in[8];
    const void* summ_b            = d_in[9];
    const void* out_W             = d_in[10];
    const void* out_b             = d_in[11];
    const int* input     = (const int*)d_in[12];
    const int* target_id = (const int*)d_in[13];

    // ws: wpack 80KB | du 33.5MB | wt_buf 32KB | readl_buf 64KB
    unsigned short* wpack = (unsigned short*)d_ws;
    __half2* du = (__half2*)(wpack + 5120 * 8);
    float* wt_buf = (float*)(du + (size_t)NCH * B_ * V_ * C_);
    float* readl_buf = wt_buf + (size_t)B_ * C_;

    dkvmn_prepack<<<148, 256, 0, stream>>>(
        erase_W, add_W, key_memory, erase_b, q_emb, target_id, wpack, wt_buf);
    dkvmn_fused<<<NCH * B_, 256, 0, stream>>>(
        q_emb, i_emb, erase_b, add_b, input, wpack, du);
    dkvmn_fold<<<4 * B_, 256, 0, stream>>>(
        init_value_memory, erase_b, du, wt_buf, readl_buf);
    dkvmn_final<<<B_, 128, 0, stream>>>(
        q_emb, summ_W, summ_b, out_W, out_b, erase_b, target_id, readl_buf, d_out);
}